// Round 14
// baseline (955.255 us; speedup 1.0000x reference)
//
#include <hip/hip_runtime.h>
#include <math.h>

#define BB 256
#define NN 128
#define DD 512
#define NEGV (-9e15f)

// ---------------------------------------------------------------- K1: star = masked mean over rows
__global__ __launch_bounds__(256) void k_avepool(const float* __restrict__ h,
                                                 const float* __restrict__ mask,
                                                 float* __restrict__ star) {
    const int b = blockIdx.x;
    const int t = threadIdx.x;
    const float* hb = h + (size_t)b * NN * DD;
    const float* mb = mask + (size_t)b * NN;
    float acc0 = 0.f, acc1 = 0.f, L = 0.f;
    for (int n = 0; n < NN; ++n) {
        float m = mb[n];
        L += m;
        acc0 += m * hb[n * DD + t];
        acc1 += m * hb[n * DD + t + 256];
    }
    star[b * DD + t] = acc0 / L;
    star[b * DD + t + 256] = acc1 / L;
}

// ---------------------------------------------------------------- K_score: symmetric scores + selection -> global esel
// grid (2, B), 512 threads, LDS 69.6KB -> 2 blocks/CU (co-resident block hides
// barrier/stage stalls). Tiles/chains exactly R11: block 0 = full tiles 0-255,
// block 1 = full tiles 256-511 (threads 0-255) + 256 quarter jobs (threads 256-511).
__global__ __launch_bounds__(512, 2) void k_score(const float* __restrict__ h_in,
                                                  const int* __restrict__ A,
                                                  const float* __restrict__ a0,
                                                  const float* __restrict__ a1,
                                                  const float* __restrict__ a2,
                                                  const float* __restrict__ a3,
                                                  float* __restrict__ esel_g) {
    __shared__ float4 hA[NN * 17];       // 34.8 KB
    __shared__ float4 hB[NN * 17];       // 34.8 KB

    const int tid = threadIdx.x;
    const int bx = blockIdx.x, b = blockIdx.y;
    const float* __restrict__ hb = h_in + (size_t)b * NN * DD;

    // ---- full-tile decode (jjb-major, R11's): tile index = bx*256 + tid, tid<256 ----
    const bool fullJob = tid < 256;
    int jjb = 0, jr = 0;
    {
        int rem = bx * 256 + (tid & 255);
        for (int k = 0; k < 16; ++k) {
            int c = 4 * k + 4;
            if (rem < c) { jjb = k; jr = rem; break; }
            rem -= c;
        }
    }
    const int i0 = jr * 2, i1 = i0 + 1;
    const int jb8 = jjb * 8;
    const int swi = (jr >> 2) & 7;
    const int swj = jjb & 7;
    // quarter decode (block 1, threads 256-511): R11's 256 quarter jobs
    const bool quarterJob = (bx == 1) && (tid >= 256);
    const int qi = tid - 256;
    const int qrow = 64 + (qi >> 2);
    const int qj0 = 120 + 2 * (qi & 3);
    const int qswi = (qrow >> 3) & 7;

    auto stageAll = [&](float4* buf, int d0) {
        #pragma unroll
        for (int q = 0; q < 4; ++q) {
            int l = q * 512 + tid;
            int row = l >> 4, c4 = l & 15;
            buf[row * 17 + (c4 ^ ((row >> 3) & 7))] = *(const float4*)(hb + row * DD + d0 + c4 * 4);
        }
    };

    float acc0[8][4], acc1[8][4];
    #pragma unroll
    for (int jj = 0; jj < 8; ++jj)
        #pragma unroll
        for (int k = 0; k < 4; ++k) { acc0[jj][k] = 0.f; acc1[jj][k] = 0.f; }

    stageAll(hA, 0);
    __syncthreads();
    for (int ck = 0; ck < 8; ++ck) {
        const int d0 = ck * 64;
        const float4* cur = (ck & 1) ? hB : hA;
        float4* nxt = (ck & 1) ? hA : hB;
        if (ck < 7) stageAll(nxt, d0 + 64);
        if (fullJob) {
            #pragma unroll 2
            for (int c4 = 0; c4 < 16; ++c4) {
                const int dbase = d0 + c4 * 4;
                const float av0x = a0[dbase],     av0y = a1[dbase],     av0z = a2[dbase],     av0w = a3[dbase];
                const float av1x = a0[dbase + 1], av1y = a1[dbase + 1], av1z = a2[dbase + 1], av1w = a3[dbase + 1];
                const float av2x = a0[dbase + 2], av2y = a1[dbase + 2], av2z = a2[dbase + 2], av2w = a3[dbase + 2];
                const float av3x = a0[dbase + 3], av3y = a1[dbase + 3], av3z = a2[dbase + 3], av3w = a3[dbase + 3];
                float4 hi0 = cur[i0 * 17 + (c4 ^ swi)];
                float4 hi1 = cur[i1 * 17 + (c4 ^ swi)];
                #pragma unroll
                for (int jj = 0; jj < 8; ++jj) {
                    float4 hj = cur[(jb8 + jj) * 17 + (c4 ^ swj)];
                    float p;
                    p = hi0.x * hj.x; acc0[jj][0] += p * av0x; acc0[jj][1] += p * av0y; acc0[jj][2] += p * av0z; acc0[jj][3] += p * av0w;
                    p = hi0.y * hj.y; acc0[jj][0] += p * av1x; acc0[jj][1] += p * av1y; acc0[jj][2] += p * av1z; acc0[jj][3] += p * av1w;
                    p = hi0.z * hj.z; acc0[jj][0] += p * av2x; acc0[jj][1] += p * av2y; acc0[jj][2] += p * av2z; acc0[jj][3] += p * av2w;
                    p = hi0.w * hj.w; acc0[jj][0] += p * av3x; acc0[jj][1] += p * av3y; acc0[jj][2] += p * av3z; acc0[jj][3] += p * av3w;
                    p = hi1.x * hj.x; acc1[jj][0] += p * av0x; acc1[jj][1] += p * av0y; acc1[jj][2] += p * av0z; acc1[jj][3] += p * av0w;
                    p = hi1.y * hj.y; acc1[jj][0] += p * av1x; acc1[jj][1] += p * av1y; acc1[jj][2] += p * av1z; acc1[jj][3] += p * av1w;
                    p = hi1.z * hj.z; acc1[jj][0] += p * av2x; acc1[jj][1] += p * av2y; acc1[jj][2] += p * av2z; acc1[jj][3] += p * av2w;
                    p = hi1.w * hj.w; acc1[jj][0] += p * av3x; acc1[jj][1] += p * av3y; acc1[jj][2] += p * av3z; acc1[jj][3] += p * av3w;
                }
            }
        } else if (quarterJob) {
            #pragma unroll 2
            for (int c4 = 0; c4 < 16; ++c4) {
                const int dbase = d0 + c4 * 4;
                const float av0x = a0[dbase],     av0y = a1[dbase],     av0z = a2[dbase],     av0w = a3[dbase];
                const float av1x = a0[dbase + 1], av1y = a1[dbase + 1], av1z = a2[dbase + 1], av1w = a3[dbase + 1];
                const float av2x = a0[dbase + 2], av2y = a1[dbase + 2], av2z = a2[dbase + 2], av2w = a3[dbase + 2];
                const float av3x = a0[dbase + 3], av3y = a1[dbase + 3], av3z = a2[dbase + 3], av3w = a3[dbase + 3];
                float4 hi0 = cur[qrow * 17 + (c4 ^ qswi)];
                #pragma unroll
                for (int jj = 0; jj < 2; ++jj) {
                    float4 hj = cur[(qj0 + jj) * 17 + (c4 ^ 7)];
                    float p;
                    p = hi0.x * hj.x; acc0[jj][0] += p * av0x; acc0[jj][1] += p * av0y; acc0[jj][2] += p * av0z; acc0[jj][3] += p * av0w;
                    p = hi0.y * hj.y; acc0[jj][0] += p * av1x; acc0[jj][1] += p * av1y; acc0[jj][2] += p * av1z; acc0[jj][3] += p * av1w;
                    p = hi0.z * hj.z; acc0[jj][0] += p * av2x; acc0[jj][1] += p * av2y; acc0[jj][2] += p * av2z; acc0[jj][3] += p * av2w;
                    p = hi0.w * hj.w; acc0[jj][0] += p * av3x; acc0[jj][1] += p * av3y; acc0[jj][2] += p * av3z; acc0[jj][3] += p * av3w;
                }
            }
        }
        __syncthreads();
    }

    // ---- selection (both triangles) -> GLOBAL esel (exact R11 selv chains) ----
    {
        auto selv = [](const float* a4, int Av) -> float {
            float e = (Av == 1) ? a4[0] : (Av == 2) ? a4[1] : (Av == 3) ? a4[2] : a4[3];
            float lr = (e > 0.f) ? e : 0.2f * e;
            return (Av >= 1 && Av <= 4) ? lr : NEGV;
        };
        const int* __restrict__ Ab = A + (size_t)b * NN * NN;
        float* __restrict__ eb = esel_g + (size_t)b * NN * NN;
        if (fullJob) {
            #pragma unroll
            for (int jj = 0; jj < 8; ++jj) {
                const int j = jb8 + jj;
                int Av;
                Av = Ab[i0 * NN + j];  eb[i0 * NN + j] = selv(acc0[jj], Av);
                Av = Ab[i1 * NN + j];  eb[i1 * NN + j] = selv(acc1[jj], Av);
                Av = Ab[j * NN + i0];  eb[j * NN + i0] = selv(acc0[jj], Av);
                Av = Ab[j * NN + i1];  eb[j * NN + i1] = selv(acc1[jj], Av);
            }
        } else if (quarterJob) {
            #pragma unroll
            for (int jj = 0; jj < 2; ++jj) {
                const int j = qj0 + jj;
                int Av;
                Av = Ab[qrow * NN + j];  eb[qrow * NN + j] = selv(acc0[jj], Av);
                Av = Ab[j * NN + qrow];  eb[j * NN + qrow] = selv(acc0[jj], Av);
            }
        }
    }
}

// ---------------------------------------------------------------- K_pv: softmax (R1 chains) + PV (R11 chains) for 64 rows
// grid (2, B), 512 threads, LDS 68.6KB -> 2 blocks/CU. All threads consume.
__global__ __launch_bounds__(512, 2) void k_pv(const float* __restrict__ h_in,
                                               const float* __restrict__ esel_g,
                                               float* __restrict__ h_gat) {
    __shared__ float4 hA[NN * 17];       // 34.8 KB
    __shared__ float  alphaS[64 * 132];  // 33.8 KB

    const int tid = threadIdx.x;
    const int bx = blockIdx.x, b = blockIdx.y;
    const int r0 = bx * 64;
    const float* __restrict__ hb = h_in + (size_t)b * NN * DD;

    // ---- softmax prologue: rows r0..r0+63, EXACT R1 trees and 16-lane groups ----
    {
        const int it2 = tid >> 8;            // 0..1 (32-row band)
        const int sub = tid & 255;
        const int ti = sub >> 4, tj = sub & 15;
        const int li0 = r0 + it2 * 32 + ti * 2, li1 = li0 + 1;
        const float* __restrict__ eb = esel_g + (size_t)b * NN * NN;
        float s0[8], s1[8];
        #pragma unroll
        for (int jj = 0; jj < 8; ++jj) {
            s0[jj] = eb[li0 * NN + tj + 16 * jj];
            s1[jj] = eb[li1 * NN + tj + 16 * jj];
        }
        float m0 = s0[0], m1 = s1[0];
        #pragma unroll
        for (int jj = 1; jj < 8; ++jj) { m0 = fmaxf(m0, s0[jj]); m1 = fmaxf(m1, s1[jj]); }
        #pragma unroll
        for (int off = 1; off < 16; off <<= 1) {
            m0 = fmaxf(m0, __shfl_xor(m0, off));
            m1 = fmaxf(m1, __shfl_xor(m1, off));
        }
        float e0[8], e1[8], sum0 = 0.f, sum1 = 0.f;
        #pragma unroll
        for (int jj = 0; jj < 8; ++jj) {
            e0[jj] = expf(s0[jj] - m0); sum0 += e0[jj];
            e1[jj] = expf(s1[jj] - m1); sum1 += e1[jj];
        }
        #pragma unroll
        for (int off = 1; off < 16; off <<= 1) {
            sum0 += __shfl_xor(sum0, off);
            sum1 += __shfl_xor(sum1, off);
        }
        #pragma unroll
        for (int jj = 0; jj < 8; ++jj) {
            alphaS[(li0 - r0) * 132 + tj + 16 * jj] = e0[jj] / sum0;
            alphaS[(li1 - r0) * 132 + tj + 16 * jj] = e1[jj] / sum1;
        }
    }

    // ---- PV: thread = (gd, jh, rsub, wv): rows r0 + wv*8 + rsub + 2t (t<4), one j-half ----
    const int gd = tid & 15, jh = (tid >> 4) & 1, rsub = (tid >> 5) & 1, wv = tid >> 6;
    const int rloc = wv * 8 + rsub;
    const int jbase = jh * 64;
#define PVROW(r, ac) { s[r].x += (ac) * hv.x; s[r].y += (ac) * hv.y; s[r].z += (ac) * hv.z; s[r].w += (ac) * hv.w; }
    for (int ck = 0; ck < 8; ++ck) {
        const int d0 = ck * 64;
        // stage hA (single buffer): 4 f4 per thread, same layout/swizzle as score
        #pragma unroll
        for (int q = 0; q < 4; ++q) {
            int l = q * 512 + tid;
            int row = l >> 4, c4 = l & 15;
            hA[row * 17 + (c4 ^ ((row >> 3) & 7))] = *(const float4*)(hb + row * DD + d0 + c4 * 4);
        }
        __syncthreads();     // also orders alphaS on first iteration
        float4 s[4];
        #pragma unroll
        for (int r = 0; r < 4; ++r) s[r] = make_float4(0.f, 0.f, 0.f, 0.f);
        #pragma unroll 2
        for (int jq = 0; jq < 16; ++jq) {
            const int j0 = jbase + jq * 4;
            const int swz = (j0 >> 3) & 7;
            float4 av0 = *(const float4*)(&alphaS[(rloc + 0) * 132 + j0]);
            float4 av1 = *(const float4*)(&alphaS[(rloc + 2) * 132 + j0]);
            float4 av2 = *(const float4*)(&alphaS[(rloc + 4) * 132 + j0]);
            float4 av3 = *(const float4*)(&alphaS[(rloc + 6) * 132 + j0]);
            float4 hv;
            hv = hA[(j0 + 0) * 17 + (gd ^ swz)];
            PVROW(0, av0.x) PVROW(1, av1.x) PVROW(2, av2.x) PVROW(3, av3.x)
            hv = hA[(j0 + 1) * 17 + (gd ^ swz)];
            PVROW(0, av0.y) PVROW(1, av1.y) PVROW(2, av2.y) PVROW(3, av3.y)
            hv = hA[(j0 + 2) * 17 + (gd ^ swz)];
            PVROW(0, av0.z) PVROW(1, av1.z) PVROW(2, av2.z) PVROW(3, av3.z)
            hv = hA[(j0 + 3) * 17 + (gd ^ swz)];
            PVROW(0, av0.w) PVROW(1, av1.w) PVROW(2, av2.w) PVROW(3, av3.w)
        }
        // merge halves: low += high (R1 order); jh==1 side discarded
        #pragma unroll
        for (int r = 0; r < 4; ++r) {
            float mx = __shfl_xor(s[r].x, 16);
            float my = __shfl_xor(s[r].y, 16);
            float mz = __shfl_xor(s[r].z, 16);
            float mw = __shfl_xor(s[r].w, 16);
            s[r].x += mx; s[r].y += my; s[r].z += mz; s[r].w += mw;
        }
        if (jh == 0) {
            float* outp = h_gat + ((size_t)b * NN + r0 + rloc) * DD + d0 + gd * 4;
            #pragma unroll
            for (int r = 0; r < 4; ++r) *(float4*)(outp + (size_t)(2 * r) * DD) = s[r];
        }
        __syncthreads();
    }
#undef PVROW
}

// ---------------------------------------------------------------- K2b: gate + noise + embs + sims (256-thread, spill-free)
__global__ __launch_bounds__(256) void k_mix(const float* __restrict__ h_gat,
                                             const float* __restrict__ star,
                                             const float* __restrict__ noise_s,
                                             const float* __restrict__ h1p,
                                             const float* __restrict__ h2p,
                                             float* __restrict__ h_out,
                                             float* __restrict__ embs,
                                             float* __restrict__ sims,
                                             int mode) {
    const int b = blockIdx.y;
    const int tid = threadIdx.x;
    const int wave = tid >> 6, lane = tid & 63;
    const int row0 = blockIdx.x * 16 + wave * 4;
    const float* stp = star + (size_t)b * DD + lane * 8;
    float4 st0 = *(const float4*)(stp);
    float4 st1 = *(const float4*)(stp + 4);
    const float inv3 = 1.0f / 3.0f;

    for (int rr = 0; rr < 4; ++rr) {
        const int row = row0 + rr;
        const size_t base = ((size_t)b * NN + row) * DD + lane * 8;
        float4 hg0 = *(const float4*)(h_gat + base);
        float4 hg1 = *(const float4*)(h_gat + base + 4);
        float4 n0 = *(const float4*)(noise_s + base);
        float4 n1 = *(const float4*)(noise_s + base + 4);
        float dot = hg0.x*st0.x + hg0.y*st0.y + hg0.z*st0.z + hg0.w*st0.w
                  + hg1.x*st1.x + hg1.y*st1.y + hg1.z*st1.z + hg1.w*st1.w;
        float nn = n0.x*n0.x + n0.y*n0.y + n0.z*n0.z + n0.w*n0.w
                 + n1.x*n1.x + n1.y*n1.y + n1.z*n1.z + n1.w*n1.w;
        #pragma unroll
        for (int off = 1; off < 64; off <<= 1) {
            dot += __shfl_xor(dot, off);
            nn  += __shfl_xor(nn, off);
        }
        const float sim = dot / 22.62741699796952f;   // / sqrt(512)
        const float al = 1.0f / (1.0f + expf(-sim));
        const float ns = 0.4f / fmaxf(sqrtf(nn), 1e-12f);

        float hm, sg, hn[8];
        float hgv[8] = {hg0.x,hg0.y,hg0.z,hg0.w,hg1.x,hg1.y,hg1.z,hg1.w};
        float stv[8] = {st0.x,st0.y,st0.z,st0.w,st1.x,st1.y,st1.z,st1.w};
        float nv [8] = {n0.x,n0.y,n0.z,n0.w,n1.x,n1.y,n1.z,n1.w};
        #pragma unroll
        for (int c = 0; c < 8; ++c) {
            hm = (1.0f - al) * hgv[c] + al * stv[c];
            sg = (hm > 0.f) ? 1.f : ((hm < 0.f) ? -1.f : 0.f);
            hn[c] = hm + sg * nv[c] * ns;
        }
        *(float4*)(h_out + base)     = make_float4(hn[0], hn[1], hn[2], hn[3]);
        *(float4*)(h_out + base + 4) = make_float4(hn[4], hn[5], hn[6], hn[7]);

        float d2 = hn[0]*stv[0] + hn[1]*stv[1] + hn[2]*stv[2] + hn[3]*stv[3]
                 + hn[4]*stv[4] + hn[5]*stv[5] + hn[6]*stv[6] + hn[7]*stv[7];
        #pragma unroll
        for (int off = 1; off < 64; off <<= 1) d2 += __shfl_xor(d2, off);
        if (lane == 0) sims[b * NN + row] = d2;

        if (mode == 1) {
            float4 a0v = *(const float4*)(h1p + base);
            float4 a1v = *(const float4*)(h1p + base + 4);
            float4 b0v = *(const float4*)(h2p + base);
            float4 b1v = *(const float4*)(h2p + base + 4);
            float h1v[8] = {a0v.x,a0v.y,a0v.z,a0v.w,a1v.x,a1v.y,a1v.z,a1v.w};
            float h2v[8] = {b0v.x,b0v.y,b0v.z,b0v.w,b1v.x,b1v.y,b1v.z,b1v.w};
            float ev[8];
            #pragma unroll
            for (int c = 0; c < 8; ++c) {
                float e = h1v[c] * inv3;
                e += h2v[c] * inv3;
                e += hn[c] * inv3;
                ev[c] = e;
            }
            *(float4*)(embs + base)     = make_float4(ev[0], ev[1], ev[2], ev[3]);
            *(float4*)(embs + base + 4) = make_float4(ev[4], ev[5], ev[6], ev[7]);
        } else if (mode == 2) {
            *(float4*)(embs + base)     = make_float4(hn[0]*inv3, hn[1]*inv3, hn[2]*inv3, hn[3]*inv3);
            *(float4*)(embs + base + 4) = make_float4(hn[4]*inv3, hn[5]*inv3, hn[6]*inv3, hn[7]*inv3);
        } else if (mode == 3) {
            float4 ea = *(const float4*)(embs + base);
            float4 eb = *(const float4*)(embs + base + 4);
            ea.x += hn[0]*inv3; ea.y += hn[1]*inv3; ea.z += hn[2]*inv3; ea.w += hn[3]*inv3;
            eb.x += hn[4]*inv3; eb.y += hn[5]*inv3; eb.z += hn[6]*inv3; eb.w += hn[7]*inv3;
            *(float4*)(embs + base)     = ea;
            *(float4*)(embs + base + 4) = eb;
        }
    }
}

// ---------------------------------------------------------------- K3: attpool from precomputed sims (one h pass)
__global__ __launch_bounds__(256) void k_attpool2(const float* __restrict__ h,
                                                  const float* __restrict__ sims,
                                                  const float* __restrict__ mask,
                                                  float* __restrict__ star_out) {
    __shared__ float simS[NN];
    __shared__ float wS[NN];
    __shared__ float sh_M, sh_inv;
    const int b = blockIdx.x;
    const int tid = threadIdx.x;
    if (tid < NN) simS[tid] = sims[b * NN + tid];
    __syncthreads();
    if (tid < 64) {
        float v = fmaxf(simS[tid], simS[tid + 64]);
        #pragma unroll
        for (int off = 1; off < 64; off <<= 1) v = fmaxf(v, __shfl_xor(v, off));
        if (tid == 0) sh_M = v;
    }
    __syncthreads();
    const float M = sh_M;
    if (tid < NN) wS[tid] = expf(simS[tid] - M) * mask[b * NN + tid];
    __syncthreads();
    if (tid < 64) {
        float v = wS[tid] + wS[tid + 64];
        #pragma unroll
        for (int off = 1; off < 64; off <<= 1) v += __shfl_xor(v, off);
        if (tid == 0) sh_inv = 1.0f / (v + 1e-24f * expf(-M));
    }
    __syncthreads();
    const float inv = sh_inv;
    const float* hb = h + (size_t)b * NN * DD;
    float acc0 = 0.f, acc1 = 0.f;
    for (int n = 0; n < NN; ++n) {
        const float w = wS[n];
        acc0 += w * hb[n * DD + tid];
        acc1 += w * hb[n * DD + tid + 256];
    }
    star_out[b * DD + tid] = acc0 * inv;
    star_out[b * DD + tid + 256] = acc1 * inv;
}

// ----------------------------------------------------------------
extern "C" void kernel_launch(void* const* d_in, const int* in_sizes, int n_in,
                              void* d_out, int out_size, void* d_ws, size_t ws_size,
                              hipStream_t stream) {
    const int*   A      = (const int*)d_in[0];
    const float* hidden = (const float*)d_in[1];
    const float* mask   = (const float*)d_in[2];
    const float* a0     = (const float*)d_in[3];
    const float* a1     = (const float*)d_in[4];
    const float* a2     = (const float*)d_in[5];
    const float* a3     = (const float*)d_in[6];
    const float* noise  = (const float*)d_in[7];

    float* out_h    = (float*)d_out;
    float* out_star = out_h + (size_t)BB * NN * DD;
    float* out_embs = out_star + (size_t)BB * DD;

    const size_t hElems = (size_t)BB * NN * DD;
    const size_t simsElems = (size_t)BB * NN;
    const size_t needDeferred = (2 * hElems + (size_t)BB * DD + simsElems) * sizeof(float);
    const bool deferred = ws_size >= needDeferred;

    float* ws_h1   = (float*)d_ws;
    float* ws_h2   = deferred ? (ws_h1 + hElems) : ws_h1;
    float* ws_star = (deferred ? ws_h2 : ws_h1) + hElems;
    float* ws_sims = ws_star + (size_t)BB * DD;
    // esel lives in the out_embs region: it is fully consumed by k_pv before
    // k_mix touches embs in each step (and in deferred mode only step 2 writes embs).
    float* g_esel  = out_embs;

    k_avepool<<<BB, 256, 0, stream>>>(hidden, mask, ws_star);

    for (int s = 0; s < 3; ++s) {
        const float* hin = (s == 0) ? hidden : (deferred ? ((s == 1) ? ws_h1 : ws_h2) : ws_h1);
        k_score<<<dim3(2, BB), 512, 0, stream>>>(hin, A, a0, a1, a2, a3, g_esel);
        k_pv<<<dim3(2, BB), 512, 0, stream>>>(hin, g_esel, out_h);

        const float* ns = noise + (size_t)s * BB * NN * DD;
        float* hout = (s == 2) ? out_h : (deferred ? ((s == 0) ? ws_h1 : ws_h2) : ws_h1);
        float* sout = (s == 2) ? out_star : ws_star;
        int mode;
        const float* h1p = nullptr; const float* h2p = nullptr;
        if (deferred) {
            if (s < 2) mode = 0;
            else { mode = 1; h1p = ws_h1; h2p = ws_h2; }
        } else {
            mode = (s == 0) ? 2 : 3;
        }
        k_mix<<<dim3(8, BB), 256, 0, stream>>>(out_h, ws_star, ns, h1p, h2p,
                                               hout, out_embs, ws_sims, mode);
        k_attpool2<<<BB, 256, 0, stream>>>(hout, ws_sims, mask, sout);
    }
}

// Round 15
// 821.948 us; speedup vs baseline: 1.1622x; 1.1622x over previous
//
#include <hip/hip_runtime.h>
#include <math.h>

#define BB 256
#define NN 128
#define DD 512
#define NEGV (-9e15f)

// ---------------------------------------------------------------- K1: star = masked mean over rows
__global__ __launch_bounds__(256) void k_avepool(const float* __restrict__ h,
                                                 const float* __restrict__ mask,
                                                 float* __restrict__ star) {
    const int b = blockIdx.x;
    const int t = threadIdx.x;
    const float* hb = h + (size_t)b * NN * DD;
    const float* mb = mask + (size_t)b * NN;
    float acc0 = 0.f, acc1 = 0.f, L = 0.f;
    for (int n = 0; n < NN; ++n) {
        float m = mb[n];
        L += m;
        acc0 += m * hb[n * DD + t];
        acc1 += m * hb[n * DD + t + 256];
    }
    star[b * DD + t] = acc0 / L;
    star[b * DD + t + 256] = acc1 / L;
}

// ---------------------------------------------------------------- K2: GAT — R11 structure (best: 224us), unroll 2->4
// Score jobs: waves 0-7 = 512 full 2x8 tiles; waves 8-11 = 256 quarter jobs
// (1 row x 2 cols); waves 12-15 idle-stage. PV: 512 consumers (wave = 16
// consecutive rows) + 512 producers. All chains bit-identical to R1.
__global__ __launch_bounds__(1024, 1) void k_gat(const float* __restrict__ h_in,
                                                 const int* __restrict__ A,
                                                 const float* __restrict__ a0,
                                                 const float* __restrict__ a1,
                                                 const float* __restrict__ a2,
                                                 const float* __restrict__ a3,
                                                 float* __restrict__ h_gat) {
    __shared__ float4 hA[NN * 17];       // 34.8 KB
    __shared__ float4 hB[NN * 17];       // 34.8 KB
    __shared__ float  eselS[NN * 132];   // 67.6 KB

    const int tid = threadIdx.x;
    const int b = blockIdx.x;
    const float* __restrict__ hb = h_in + (size_t)b * NN * DD;

    // ---- full-tile decode, jjb-major: tiles 0..511 = tid 0..511 ----
    const bool fullJob = tid < 512;
    const bool quarterJob = (tid >= 512) && (tid < 768);
    int jjb = 0, jr = 0;
    if (fullJob) {
        int rem = tid;
        for (int k = 0; k < 16; ++k) {
            int c = 4 * k + 4;
            if (rem < c) { jjb = k; jr = rem; break; }
            rem -= c;
        }
    }
    const int i0 = jr * 2, i1 = i0 + 1;
    const int jb8 = jjb * 8;
    const int swi = (jr >> 2) & 7;
    const int swj = jjb & 7;
    // quarter decode: q = tid-512: row 64+(q>>2), cols 120+2*(q&3), 121+2*(q&3)
    const int qi = tid - 512;
    const int qrow = 64 + (qi >> 2);
    const int qj0 = 120 + 2 * (qi & 3);
    const int qswi = (qrow >> 3) & 7;

    auto stageAll = [&](float4* buf, int d0) {
        #pragma unroll
        for (int q = 0; q < 2; ++q) {
            int l = q * 1024 + tid;
            int row = l >> 4, c4 = l & 15;
            buf[row * 17 + (c4 ^ ((row >> 3) & 7))] = *(const float4*)(hb + row * DD + d0 + c4 * 4);
        }
    };

    float acc0[8][4], acc1[8][4];
    #pragma unroll
    for (int jj = 0; jj < 8; ++jj)
        #pragma unroll
        for (int k = 0; k < 4; ++k) { acc0[jj][k] = 0.f; acc1[jj][k] = 0.f; }

    // ================= score phase (chains exactly R1 per pair; dbuf all-thread staging) =================
    stageAll(hA, 0);
    __syncthreads();
    for (int ck = 0; ck < 8; ++ck) {
        const int d0 = ck * 64;
        const float4* cur = (ck & 1) ? hB : hA;
        float4* nxt = (ck & 1) ? hA : hB;
        if (ck < 7) stageAll(nxt, d0 + 64);
        if (fullJob) {
            #pragma unroll 4
            for (int c4 = 0; c4 < 16; ++c4) {
                const int dbase = d0 + c4 * 4;
                const float av0x = a0[dbase],     av0y = a1[dbase],     av0z = a2[dbase],     av0w = a3[dbase];
                const float av1x = a0[dbase + 1], av1y = a1[dbase + 1], av1z = a2[dbase + 1], av1w = a3[dbase + 1];
                const float av2x = a0[dbase + 2], av2y = a1[dbase + 2], av2z = a2[dbase + 2], av2w = a3[dbase + 2];
                const float av3x = a0[dbase + 3], av3y = a1[dbase + 3], av3z = a2[dbase + 3], av3w = a3[dbase + 3];
                float4 hi0 = cur[i0 * 17 + (c4 ^ swi)];
                float4 hi1 = cur[i1 * 17 + (c4 ^ swi)];
                #pragma unroll
                for (int jj = 0; jj < 8; ++jj) {
                    float4 hj = cur[(jb8 + jj) * 17 + (c4 ^ swj)];
                    float p;
                    p = hi0.x * hj.x; acc0[jj][0] += p * av0x; acc0[jj][1] += p * av0y; acc0[jj][2] += p * av0z; acc0[jj][3] += p * av0w;
                    p = hi0.y * hj.y; acc0[jj][0] += p * av1x; acc0[jj][1] += p * av1y; acc0[jj][2] += p * av1z; acc0[jj][3] += p * av1w;
                    p = hi0.z * hj.z; acc0[jj][0] += p * av2x; acc0[jj][1] += p * av2y; acc0[jj][2] += p * av2z; acc0[jj][3] += p * av2w;
                    p = hi0.w * hj.w; acc0[jj][0] += p * av3x; acc0[jj][1] += p * av3y; acc0[jj][2] += p * av3z; acc0[jj][3] += p * av3w;
                    p = hi1.x * hj.x; acc1[jj][0] += p * av0x; acc1[jj][1] += p * av0y; acc1[jj][2] += p * av0z; acc1[jj][3] += p * av0w;
                    p = hi1.y * hj.y; acc1[jj][0] += p * av1x; acc1[jj][1] += p * av1y; acc1[jj][2] += p * av1z; acc1[jj][3] += p * av1w;
                    p = hi1.z * hj.z; acc1[jj][0] += p * av2x; acc1[jj][1] += p * av2y; acc1[jj][2] += p * av2z; acc1[jj][3] += p * av2w;
                    p = hi1.w * hj.w; acc1[jj][0] += p * av3x; acc1[jj][1] += p * av3y; acc1[jj][2] += p * av3z; acc1[jj][3] += p * av3w;
                }
            }
        } else if (quarterJob) {
            #pragma unroll 4
            for (int c4 = 0; c4 < 16; ++c4) {
                const int dbase = d0 + c4 * 4;
                const float av0x = a0[dbase],     av0y = a1[dbase],     av0z = a2[dbase],     av0w = a3[dbase];
                const float av1x = a0[dbase + 1], av1y = a1[dbase + 1], av1z = a2[dbase + 1], av1w = a3[dbase + 1];
                const float av2x = a0[dbase + 2], av2y = a1[dbase + 2], av2z = a2[dbase + 2], av2w = a3[dbase + 2];
                const float av3x = a0[dbase + 3], av3y = a1[dbase + 3], av3z = a2[dbase + 3], av3w = a3[dbase + 3];
                float4 hi0 = cur[qrow * 17 + (c4 ^ qswi)];
                #pragma unroll
                for (int jj = 0; jj < 2; ++jj) {
                    float4 hj = cur[(qj0 + jj) * 17 + (c4 ^ 7)];
                    float p;
                    p = hi0.x * hj.x; acc0[jj][0] += p * av0x; acc0[jj][1] += p * av0y; acc0[jj][2] += p * av0z; acc0[jj][3] += p * av0w;
                    p = hi0.y * hj.y; acc0[jj][0] += p * av1x; acc0[jj][1] += p * av1y; acc0[jj][2] += p * av1z; acc0[jj][3] += p * av1w;
                    p = hi0.z * hj.z; acc0[jj][0] += p * av2x; acc0[jj][1] += p * av2y; acc0[jj][2] += p * av2z; acc0[jj][3] += p * av2w;
                    p = hi0.w * hj.w; acc0[jj][0] += p * av3x; acc0[jj][1] += p * av3y; acc0[jj][2] += p * av3z; acc0[jj][3] += p * av3w;
                }
            }
        }
        __syncthreads();
    }

    // ================= selection (both triangles) -> esel =================
    {
        auto selv = [](const float* a4, int Av) -> float {
            float e = (Av == 1) ? a4[0] : (Av == 2) ? a4[1] : (Av == 3) ? a4[2] : a4[3];
            float lr = (e > 0.f) ? e : 0.2f * e;
            return (Av >= 1 && Av <= 4) ? lr : NEGV;
        };
        const int* __restrict__ Ab = A + (size_t)b * NN * NN;
        if (fullJob) {
            #pragma unroll
            for (int jj = 0; jj < 8; ++jj) {
                const int j = jb8 + jj;
                int Av;
                Av = Ab[i0 * NN + j];  eselS[i0 * 132 + j] = selv(acc0[jj], Av);
                Av = Ab[i1 * NN + j];  eselS[i1 * 132 + j] = selv(acc1[jj], Av);
                Av = Ab[j * NN + i0];  eselS[j * 132 + i0] = selv(acc0[jj], Av);
                Av = Ab[j * NN + i1];  eselS[j * 132 + i1] = selv(acc1[jj], Av);
            }
        } else if (quarterJob) {
            #pragma unroll
            for (int jj = 0; jj < 2; ++jj) {
                const int j = qj0 + jj;
                int Av;
                Av = Ab[qrow * NN + j];  eselS[qrow * 132 + j] = selv(acc0[jj], Av);
                Av = Ab[j * NN + qrow];  eselS[j * 132 + qrow] = selv(acc0[jj], Av);
            }
        }
        __syncthreads();
    }

    // ================= row softmax — EXACTLY R1's tree and lane mapping =================
    {
        const int it4 = tid >> 8;
        const int sub = tid & 255;
        const int ti = sub >> 4, tj = sub & 15;
        const int li0 = it4 * 32 + ti * 2, li1 = li0 + 1;
        float s0[8], s1[8];
        #pragma unroll
        for (int jj = 0; jj < 8; ++jj) {
            s0[jj] = eselS[li0 * 132 + tj + 16 * jj];
            s1[jj] = eselS[li1 * 132 + tj + 16 * jj];
        }
        float m0 = s0[0], m1 = s1[0];
        #pragma unroll
        for (int jj = 1; jj < 8; ++jj) { m0 = fmaxf(m0, s0[jj]); m1 = fmaxf(m1, s1[jj]); }
        #pragma unroll
        for (int off = 1; off < 16; off <<= 1) {
            m0 = fmaxf(m0, __shfl_xor(m0, off));
            m1 = fmaxf(m1, __shfl_xor(m1, off));
        }
        float e0[8], e1[8], sum0 = 0.f, sum1 = 0.f;
        #pragma unroll
        for (int jj = 0; jj < 8; ++jj) {
            e0[jj] = expf(s0[jj] - m0); sum0 += e0[jj];
            e1[jj] = expf(s1[jj] - m1); sum1 += e1[jj];
        }
        #pragma unroll
        for (int off = 1; off < 16; off <<= 1) {
            sum0 += __shfl_xor(sum0, off);
            sum1 += __shfl_xor(sum1, off);
        }
        #pragma unroll
        for (int jj = 0; jj < 8; ++jj) {
            eselS[li0 * 132 + tj + 16 * jj] = e0[jj] / sum0;
            eselS[li1 * 132 + tj + 16 * jj] = e1[jj] / sum1;
        }
    }
    __syncthreads();

    // ================= PV: 512 consumers (wave = 16 consecutive rows) + 512 producers =================
    stageAll(hA, 0);
    __syncthreads();
    const int gd = tid & 15, jh = (tid >> 4) & 1, rsub = (tid >> 5) & 1, wv = tid >> 6;
    const int rbase = wv * 16 + rsub;          // rows rbase + 2t
    const int jbase = jh * 64;
#define PVROW(r, ac) { s[r].x += (ac) * hv.x; s[r].y += (ac) * hv.y; s[r].z += (ac) * hv.z; s[r].w += (ac) * hv.w; }
    for (int ck = 0; ck < 8; ++ck) {
        const int d0 = ck * 64;
        const float4* cur = (ck & 1) ? hB : hA;
        float4* nxt = (ck & 1) ? hA : hB;
        if (tid >= 512) {
            if (ck < 7) {
                #pragma unroll
                for (int q = 0; q < 4; ++q) {
                    int l = q * 512 + (tid - 512);
                    int row = l >> 4, c4 = l & 15;
                    nxt[row * 17 + (c4 ^ ((row >> 3) & 7))] = *(const float4*)(hb + row * DD + d0 + 64 + c4 * 4);
                }
            }
        } else {
            float4 s[8];
            #pragma unroll
            for (int r = 0; r < 8; ++r) s[r] = make_float4(0.f, 0.f, 0.f, 0.f);
            #pragma unroll 4
            for (int jq = 0; jq < 16; ++jq) {
                const int j0 = jbase + jq * 4;
                const int swz = (j0 >> 3) & 7;
                float4 av0 = *(const float4*)(&eselS[(rbase +  0) * 132 + j0]);
                float4 av1 = *(const float4*)(&eselS[(rbase +  2) * 132 + j0]);
                float4 av2 = *(const float4*)(&eselS[(rbase +  4) * 132 + j0]);
                float4 av3 = *(const float4*)(&eselS[(rbase +  6) * 132 + j0]);
                float4 av4 = *(const float4*)(&eselS[(rbase +  8) * 132 + j0]);
                float4 av5 = *(const float4*)(&eselS[(rbase + 10) * 132 + j0]);
                float4 av6 = *(const float4*)(&eselS[(rbase + 12) * 132 + j0]);
                float4 av7 = *(const float4*)(&eselS[(rbase + 14) * 132 + j0]);
                float4 hv;
                hv = cur[(j0 + 0) * 17 + (gd ^ swz)];
                PVROW(0, av0.x) PVROW(1, av1.x) PVROW(2, av2.x) PVROW(3, av3.x)
                PVROW(4, av4.x) PVROW(5, av5.x) PVROW(6, av6.x) PVROW(7, av7.x)
                hv = cur[(j0 + 1) * 17 + (gd ^ swz)];
                PVROW(0, av0.y) PVROW(1, av1.y) PVROW(2, av2.y) PVROW(3, av3.y)
                PVROW(4, av4.y) PVROW(5, av5.y) PVROW(6, av6.y) PVROW(7, av7.y)
                hv = cur[(j0 + 2) * 17 + (gd ^ swz)];
                PVROW(0, av0.z) PVROW(1, av1.z) PVROW(2, av2.z) PVROW(3, av3.z)
                PVROW(4, av4.z) PVROW(5, av5.z) PVROW(6, av6.z) PVROW(7, av7.z)
                hv = cur[(j0 + 3) * 17 + (gd ^ swz)];
                PVROW(0, av0.w) PVROW(1, av1.w) PVROW(2, av2.w) PVROW(3, av3.w)
                PVROW(4, av4.w) PVROW(5, av5.w) PVROW(6, av6.w) PVROW(7, av7.w)
            }
            #pragma unroll
            for (int r = 0; r < 8; ++r) {
                float mx = __shfl_xor(s[r].x, 16);
                float my = __shfl_xor(s[r].y, 16);
                float mz = __shfl_xor(s[r].z, 16);
                float mw = __shfl_xor(s[r].w, 16);
                s[r].x += mx; s[r].y += my; s[r].z += mz; s[r].w += mw;
            }
            if (jh == 0) {
                float* outp = h_gat + ((size_t)b * NN + rbase) * DD + d0 + gd * 4;
                #pragma unroll
                for (int r = 0; r < 8; ++r) *(float4*)(outp + (size_t)(2 * r) * DD) = s[r];
            }
        }
        __syncthreads();
    }
#undef PVROW
}

// ---------------------------------------------------------------- K2b: gate + noise + embs + sims (256-thread, spill-free)
// grid (8, B). Chains exactly R1 k_mix; sim = exact R1 k_attpool dot chain on hn.
// mode: 0 = no embs; 1 = deferred final (embs from h1,h2,hn); 2 = embs = hn/3; 3 = embs += hn/3.
__global__ __launch_bounds__(256) void k_mix(const float* __restrict__ h_gat,
                                             const float* __restrict__ star,
                                             const float* __restrict__ noise_s,
                                             const float* __restrict__ h1p,
                                             const float* __restrict__ h2p,
                                             float* __restrict__ h_out,
                                             float* __restrict__ embs,
                                             float* __restrict__ sims,
                                             int mode) {
    const int b = blockIdx.y;
    const int tid = threadIdx.x;
    const int wave = tid >> 6, lane = tid & 63;
    const int row0 = blockIdx.x * 16 + wave * 4;
    const float* stp = star + (size_t)b * DD + lane * 8;
    float4 st0 = *(const float4*)(stp);
    float4 st1 = *(const float4*)(stp + 4);
    const float inv3 = 1.0f / 3.0f;

    for (int rr = 0; rr < 4; ++rr) {
        const int row = row0 + rr;
        const size_t base = ((size_t)b * NN + row) * DD + lane * 8;
        float4 hg0 = *(const float4*)(h_gat + base);
        float4 hg1 = *(const float4*)(h_gat + base + 4);
        float4 n0 = *(const float4*)(noise_s + base);
        float4 n1 = *(const float4*)(noise_s + base + 4);
        float dot = hg0.x*st0.x + hg0.y*st0.y + hg0.z*st0.z + hg0.w*st0.w
                  + hg1.x*st1.x + hg1.y*st1.y + hg1.z*st1.z + hg1.w*st1.w;
        float nn = n0.x*n0.x + n0.y*n0.y + n0.z*n0.z + n0.w*n0.w
                 + n1.x*n1.x + n1.y*n1.y + n1.z*n1.z + n1.w*n1.w;
        #pragma unroll
        for (int off = 1; off < 64; off <<= 1) {
            dot += __shfl_xor(dot, off);
            nn  += __shfl_xor(nn, off);
        }
        const float sim = dot / 22.62741699796952f;   // / sqrt(512)
        const float al = 1.0f / (1.0f + expf(-sim));
        const float ns = 0.4f / fmaxf(sqrtf(nn), 1e-12f);

        float hm, sg, hn[8];
        float hgv[8] = {hg0.x,hg0.y,hg0.z,hg0.w,hg1.x,hg1.y,hg1.z,hg1.w};
        float stv[8] = {st0.x,st0.y,st0.z,st0.w,st1.x,st1.y,st1.z,st1.w};
        float nv [8] = {n0.x,n0.y,n0.z,n0.w,n1.x,n1.y,n1.z,n1.w};
        #pragma unroll
        for (int c = 0; c < 8; ++c) {
            hm = (1.0f - al) * hgv[c] + al * stv[c];
            sg = (hm > 0.f) ? 1.f : ((hm < 0.f) ? -1.f : 0.f);
            hn[c] = hm + sg * nv[c] * ns;
        }
        *(float4*)(h_out + base)     = make_float4(hn[0], hn[1], hn[2], hn[3]);
        *(float4*)(h_out + base + 4) = make_float4(hn[4], hn[5], hn[6], hn[7]);

        float d2 = hn[0]*stv[0] + hn[1]*stv[1] + hn[2]*stv[2] + hn[3]*stv[3]
                 + hn[4]*stv[4] + hn[5]*stv[5] + hn[6]*stv[6] + hn[7]*stv[7];
        #pragma unroll
        for (int off = 1; off < 64; off <<= 1) d2 += __shfl_xor(d2, off);
        if (lane == 0) sims[b * NN + row] = d2;

        if (mode == 1) {
            float4 a0v = *(const float4*)(h1p + base);
            float4 a1v = *(const float4*)(h1p + base + 4);
            float4 b0v = *(const float4*)(h2p + base);
            float4 b1v = *(const float4*)(h2p + base + 4);
            float h1v[8] = {a0v.x,a0v.y,a0v.z,a0v.w,a1v.x,a1v.y,a1v.z,a1v.w};
            float h2v[8] = {b0v.x,b0v.y,b0v.z,b0v.w,b1v.x,b1v.y,b1v.z,b1v.w};
            float ev[8];
            #pragma unroll
            for (int c = 0; c < 8; ++c) {
                float e = h1v[c] * inv3;
                e += h2v[c] * inv3;
                e += hn[c] * inv3;
                ev[c] = e;
            }
            *(float4*)(embs + base)     = make_float4(ev[0], ev[1], ev[2], ev[3]);
            *(float4*)(embs + base + 4) = make_float4(ev[4], ev[5], ev[6], ev[7]);
        } else if (mode == 2) {
            *(float4*)(embs + base)     = make_float4(hn[0]*inv3, hn[1]*inv3, hn[2]*inv3, hn[3]*inv3);
            *(float4*)(embs + base + 4) = make_float4(hn[4]*inv3, hn[5]*inv3, hn[6]*inv3, hn[7]*inv3);
        } else if (mode == 3) {
            float4 ea = *(const float4*)(embs + base);
            float4 eb = *(const float4*)(embs + base + 4);
            ea.x += hn[0]*inv3; ea.y += hn[1]*inv3; ea.z += hn[2]*inv3; ea.w += hn[3]*inv3;
            eb.x += hn[4]*inv3; eb.y += hn[5]*inv3; eb.z += hn[6]*inv3; eb.w += hn[7]*inv3;
            *(float4*)(embs + base)     = ea;
            *(float4*)(embs + base + 4) = eb;
        }
    }
}

// ---------------------------------------------------------------- K3: attpool from precomputed sims (one h pass)
__global__ __launch_bounds__(256) void k_attpool2(const float* __restrict__ h,
                                                  const float* __restrict__ sims,
                                                  const float* __restrict__ mask,
                                                  float* __restrict__ star_out) {
    __shared__ float simS[NN];
    __shared__ float wS[NN];
    __shared__ float sh_M, sh_inv;
    const int b = blockIdx.x;
    const int tid = threadIdx.x;
    if (tid < NN) simS[tid] = sims[b * NN + tid];
    __syncthreads();
    if (tid < 64) {
        float v = fmaxf(simS[tid], simS[tid + 64]);
        #pragma unroll
        for (int off = 1; off < 64; off <<= 1) v = fmaxf(v, __shfl_xor(v, off));
        if (tid == 0) sh_M = v;
    }
    __syncthreads();
    const float M = sh_M;
    if (tid < NN) wS[tid] = expf(simS[tid] - M) * mask[b * NN + tid];
    __syncthreads();
    if (tid < 64) {
        float v = wS[tid] + wS[tid + 64];
        #pragma unroll
        for (int off = 1; off < 64; off <<= 1) v += __shfl_xor(v, off);
        if (tid == 0) sh_inv = 1.0f / (v + 1e-24f * expf(-M));
    }
    __syncthreads();
    const float inv = sh_inv;
    const float* hb = h + (size_t)b * NN * DD;
    float acc0 = 0.f, acc1 = 0.f;
    for (int n = 0; n < NN; ++n) {
        const float w = wS[n];
        acc0 += w * hb[n * DD + tid];
        acc1 += w * hb[n * DD + tid + 256];
    }
    star_out[b * DD + tid] = acc0 * inv;
    star_out[b * DD + tid + 256] = acc1 * inv;
}

// ----------------------------------------------------------------
extern "C" void kernel_launch(void* const* d_in, const int* in_sizes, int n_in,
                              void* d_out, int out_size, void* d_ws, size_t ws_size,
                              hipStream_t stream) {
    const int*   A      = (const int*)d_in[0];
    const float* hidden = (const float*)d_in[1];
    const float* mask   = (const float*)d_in[2];
    const float* a0     = (const float*)d_in[3];
    const float* a1     = (const float*)d_in[4];
    const float* a2     = (const float*)d_in[5];
    const float* a3     = (const float*)d_in[6];
    const float* noise  = (const float*)d_in[7];

    float* out_h    = (float*)d_out;
    float* out_star = out_h + (size_t)BB * NN * DD;
    float* out_embs = out_star + (size_t)BB * DD;

    const size_t hElems = (size_t)BB * NN * DD;
    const size_t simsElems = (size_t)BB * NN;
    const size_t needDeferred = (2 * hElems + (size_t)BB * DD + simsElems) * sizeof(float);
    const bool deferred = ws_size >= needDeferred;

    float* ws_h1   = (float*)d_ws;
    float* ws_h2   = deferred ? (ws_h1 + hElems) : ws_h1;
    float* ws_star = (deferred ? ws_h2 : ws_h1) + hElems;
    float* ws_sims = ws_star + (size_t)BB * DD;

    k_avepool<<<BB, 256, 0, stream>>>(hidden, mask, ws_star);

    for (int s = 0; s < 3; ++s) {
        const float* hin = (s == 0) ? hidden : (deferred ? ((s == 1) ? ws_h1 : ws_h2) : ws_h1);
        k_gat<<<BB, 1024, 0, stream>>>(hin, A, a0, a1, a2, a3, out_h);

        const float* ns = noise + (size_t)s * BB * NN * DD;
        float* hout = (s == 2) ? out_h : (deferred ? ((s == 0) ? ws_h1 : ws_h2) : ws_h1);
        float* sout = (s == 2) ? out_star : ws_star;
        int mode;
        const float* h1p = nullptr; const float* h2p = nullptr;
        if (deferred) {
            if (s < 2) mode = 0;
            else { mode = 1; h1p = ws_h1; h2p = ws_h2; }
        } else {
            mode = (s == 0) ? 2 : 3;
        }
        k_mix<<<dim3(8, BB), 256, 0, stream>>>(out_h, ws_star, ns, h1p, h2p,
                                               hout, out_embs, ws_sims, mode);
        k_attpool2<<<BB, 256, 0, stream>>>(hout, ws_sims, mask, sout);
    }
}

// Round 16
// 779.223 us; speedup vs baseline: 1.2259x; 1.0548x over previous
//
#include <hip/hip_runtime.h>
#include <math.h>

#define BB 256
#define NN 128
#define DD 512
#define NEGV (-9e15f)

// ---------------------------------------------------------------- K1: star = masked mean over rows
__global__ __launch_bounds__(256) void k_avepool(const float* __restrict__ h,
                                                 const float* __restrict__ mask,
                                                 float* __restrict__ star) {
    const int b = blockIdx.x;
    const int t = threadIdx.x;
    const float* hb = h + (size_t)b * NN * DD;
    const float* mb = mask + (size_t)b * NN;
    float acc0 = 0.f, acc1 = 0.f, L = 0.f;
    for (int n = 0; n < NN; ++n) {
        float m = mb[n];
        L += m;
        acc0 += m * hb[n * DD + t];
        acc1 += m * hb[n * DD + t + 256];
    }
    star[b * DD + t] = acc0 / L;
    star[b * DD + t + 256] = acc1 / L;
}

// ---------------------------------------------------------------- K2: GAT — R11 structure (best verified: 224us, total 782us)
// Score jobs: waves 0-7 = 512 full 2x8 tiles; waves 8-11 = 256 quarter jobs
// (1 row x 2 cols); waves 12-15 idle-stage. PV: 512 consumers (wave = 16
// consecutive rows) + 512 producers. All chains bit-identical to R1.
__global__ __launch_bounds__(1024, 1) void k_gat(const float* __restrict__ h_in,
                                                 const int* __restrict__ A,
                                                 const float* __restrict__ a0,
                                                 const float* __restrict__ a1,
                                                 const float* __restrict__ a2,
                                                 const float* __restrict__ a3,
                                                 float* __restrict__ h_gat) {
    __shared__ float4 hA[NN * 17];       // 34.8 KB
    __shared__ float4 hB[NN * 17];       // 34.8 KB
    __shared__ float  eselS[NN * 132];   // 67.6 KB

    const int tid = threadIdx.x;
    const int b = blockIdx.x;
    const float* __restrict__ hb = h_in + (size_t)b * NN * DD;

    // ---- full-tile decode, jjb-major: tiles 0..511 = tid 0..511 ----
    const bool fullJob = tid < 512;
    const bool quarterJob = (tid >= 512) && (tid < 768);
    int jjb = 0, jr = 0;
    if (fullJob) {
        int rem = tid;
        for (int k = 0; k < 16; ++k) {
            int c = 4 * k + 4;
            if (rem < c) { jjb = k; jr = rem; break; }
            rem -= c;
        }
    }
    const int i0 = jr * 2, i1 = i0 + 1;
    const int jb8 = jjb * 8;
    const int swi = (jr >> 2) & 7;
    const int swj = jjb & 7;
    // quarter decode: q = tid-512: row 64+(q>>2), cols 120+2*(q&3), 121+2*(q&3)
    const int qi = tid - 512;
    const int qrow = 64 + (qi >> 2);
    const int qj0 = 120 + 2 * (qi & 3);
    const int qswi = (qrow >> 3) & 7;

    auto stageAll = [&](float4* buf, int d0) {
        #pragma unroll
        for (int q = 0; q < 2; ++q) {
            int l = q * 1024 + tid;
            int row = l >> 4, c4 = l & 15;
            buf[row * 17 + (c4 ^ ((row >> 3) & 7))] = *(const float4*)(hb + row * DD + d0 + c4 * 4);
        }
    };

    float acc0[8][4], acc1[8][4];
    #pragma unroll
    for (int jj = 0; jj < 8; ++jj)
        #pragma unroll
        for (int k = 0; k < 4; ++k) { acc0[jj][k] = 0.f; acc1[jj][k] = 0.f; }

    // ================= score phase (chains exactly R1 per pair; dbuf all-thread staging) =================
    stageAll(hA, 0);
    __syncthreads();
    for (int ck = 0; ck < 8; ++ck) {
        const int d0 = ck * 64;
        const float4* cur = (ck & 1) ? hB : hA;
        float4* nxt = (ck & 1) ? hA : hB;
        if (ck < 7) stageAll(nxt, d0 + 64);
        if (fullJob) {
            #pragma unroll 2
            for (int c4 = 0; c4 < 16; ++c4) {
                const int dbase = d0 + c4 * 4;
                const float av0x = a0[dbase],     av0y = a1[dbase],     av0z = a2[dbase],     av0w = a3[dbase];
                const float av1x = a0[dbase + 1], av1y = a1[dbase + 1], av1z = a2[dbase + 1], av1w = a3[dbase + 1];
                const float av2x = a0[dbase + 2], av2y = a1[dbase + 2], av2z = a2[dbase + 2], av2w = a3[dbase + 2];
                const float av3x = a0[dbase + 3], av3y = a1[dbase + 3], av3z = a2[dbase + 3], av3w = a3[dbase + 3];
                float4 hi0 = cur[i0 * 17 + (c4 ^ swi)];
                float4 hi1 = cur[i1 * 17 + (c4 ^ swi)];
                #pragma unroll
                for (int jj = 0; jj < 8; ++jj) {
                    float4 hj = cur[(jb8 + jj) * 17 + (c4 ^ swj)];
                    float p;
                    p = hi0.x * hj.x; acc0[jj][0] += p * av0x; acc0[jj][1] += p * av0y; acc0[jj][2] += p * av0z; acc0[jj][3] += p * av0w;
                    p = hi0.y * hj.y; acc0[jj][0] += p * av1x; acc0[jj][1] += p * av1y; acc0[jj][2] += p * av1z; acc0[jj][3] += p * av1w;
                    p = hi0.z * hj.z; acc0[jj][0] += p * av2x; acc0[jj][1] += p * av2y; acc0[jj][2] += p * av2z; acc0[jj][3] += p * av2w;
                    p = hi0.w * hj.w; acc0[jj][0] += p * av3x; acc0[jj][1] += p * av3y; acc0[jj][2] += p * av3z; acc0[jj][3] += p * av3w;
                    p = hi1.x * hj.x; acc1[jj][0] += p * av0x; acc1[jj][1] += p * av0y; acc1[jj][2] += p * av0z; acc1[jj][3] += p * av0w;
                    p = hi1.y * hj.y; acc1[jj][0] += p * av1x; acc1[jj][1] += p * av1y; acc1[jj][2] += p * av1z; acc1[jj][3] += p * av1w;
                    p = hi1.z * hj.z; acc1[jj][0] += p * av2x; acc1[jj][1] += p * av2y; acc1[jj][2] += p * av2z; acc1[jj][3] += p * av2w;
                    p = hi1.w * hj.w; acc1[jj][0] += p * av3x; acc1[jj][1] += p * av3y; acc1[jj][2] += p * av3z; acc1[jj][3] += p * av3w;
                }
            }
        } else if (quarterJob) {
            #pragma unroll 2
            for (int c4 = 0; c4 < 16; ++c4) {
                const int dbase = d0 + c4 * 4;
                const float av0x = a0[dbase],     av0y = a1[dbase],     av0z = a2[dbase],     av0w = a3[dbase];
                const float av1x = a0[dbase + 1], av1y = a1[dbase + 1], av1z = a2[dbase + 1], av1w = a3[dbase + 1];
                const float av2x = a0[dbase + 2], av2y = a1[dbase + 2], av2z = a2[dbase + 2], av2w = a3[dbase + 2];
                const float av3x = a0[dbase + 3], av3y = a1[dbase + 3], av3z = a2[dbase + 3], av3w = a3[dbase + 3];
                float4 hi0 = cur[qrow * 17 + (c4 ^ qswi)];
                #pragma unroll
                for (int jj = 0; jj < 2; ++jj) {
                    float4 hj = cur[(qj0 + jj) * 17 + (c4 ^ 7)];
                    float p;
                    p = hi0.x * hj.x; acc0[jj][0] += p * av0x; acc0[jj][1] += p * av0y; acc0[jj][2] += p * av0z; acc0[jj][3] += p * av0w;
                    p = hi0.y * hj.y; acc0[jj][0] += p * av1x; acc0[jj][1] += p * av1y; acc0[jj][2] += p * av1z; acc0[jj][3] += p * av1w;
                    p = hi0.z * hj.z; acc0[jj][0] += p * av2x; acc0[jj][1] += p * av2y; acc0[jj][2] += p * av2z; acc0[jj][3] += p * av2w;
                    p = hi0.w * hj.w; acc0[jj][0] += p * av3x; acc0[jj][1] += p * av3y; acc0[jj][2] += p * av3z; acc0[jj][3] += p * av3w;
                }
            }
        }
        __syncthreads();
    }

    // ================= selection (both triangles) -> esel =================
    {
        auto selv = [](const float* a4, int Av) -> float {
            float e = (Av == 1) ? a4[0] : (Av == 2) ? a4[1] : (Av == 3) ? a4[2] : a4[3];
            float lr = (e > 0.f) ? e : 0.2f * e;
            return (Av >= 1 && Av <= 4) ? lr : NEGV;
        };
        const int* __restrict__ Ab = A + (size_t)b * NN * NN;
        if (fullJob) {
            #pragma unroll
            for (int jj = 0; jj < 8; ++jj) {
                const int j = jb8 + jj;
                int Av;
                Av = Ab[i0 * NN + j];  eselS[i0 * 132 + j] = selv(acc0[jj], Av);
                Av = Ab[i1 * NN + j];  eselS[i1 * 132 + j] = selv(acc1[jj], Av);
                Av = Ab[j * NN + i0];  eselS[j * 132 + i0] = selv(acc0[jj], Av);
                Av = Ab[j * NN + i1];  eselS[j * 132 + i1] = selv(acc1[jj], Av);
            }
        } else if (quarterJob) {
            #pragma unroll
            for (int jj = 0; jj < 2; ++jj) {
                const int j = qj0 + jj;
                int Av;
                Av = Ab[qrow * NN + j];  eselS[qrow * 132 + j] = selv(acc0[jj], Av);
                Av = Ab[j * NN + qrow];  eselS[j * 132 + qrow] = selv(acc0[jj], Av);
            }
        }
        __syncthreads();
    }

    // ================= row softmax — EXACTLY R1's tree and lane mapping =================
    {
        const int it4 = tid >> 8;
        const int sub = tid & 255;
        const int ti = sub >> 4, tj = sub & 15;
        const int li0 = it4 * 32 + ti * 2, li1 = li0 + 1;
        float s0[8], s1[8];
        #pragma unroll
        for (int jj = 0; jj < 8; ++jj) {
            s0[jj] = eselS[li0 * 132 + tj + 16 * jj];
            s1[jj] = eselS[li1 * 132 + tj + 16 * jj];
        }
        float m0 = s0[0], m1 = s1[0];
        #pragma unroll
        for (int jj = 1; jj < 8; ++jj) { m0 = fmaxf(m0, s0[jj]); m1 = fmaxf(m1, s1[jj]); }
        #pragma unroll
        for (int off = 1; off < 16; off <<= 1) {
            m0 = fmaxf(m0, __shfl_xor(m0, off));
            m1 = fmaxf(m1, __shfl_xor(m1, off));
        }
        float e0[8], e1[8], sum0 = 0.f, sum1 = 0.f;
        #pragma unroll
        for (int jj = 0; jj < 8; ++jj) {
            e0[jj] = expf(s0[jj] - m0); sum0 += e0[jj];
            e1[jj] = expf(s1[jj] - m1); sum1 += e1[jj];
        }
        #pragma unroll
        for (int off = 1; off < 16; off <<= 1) {
            sum0 += __shfl_xor(sum0, off);
            sum1 += __shfl_xor(sum1, off);
        }
        #pragma unroll
        for (int jj = 0; jj < 8; ++jj) {
            eselS[li0 * 132 + tj + 16 * jj] = e0[jj] / sum0;
            eselS[li1 * 132 + tj + 16 * jj] = e1[jj] / sum1;
        }
    }
    __syncthreads();

    // ================= PV: 512 consumers (wave = 16 consecutive rows) + 512 producers =================
    stageAll(hA, 0);
    __syncthreads();
    const int gd = tid & 15, jh = (tid >> 4) & 1, rsub = (tid >> 5) & 1, wv = tid >> 6;
    const int rbase = wv * 16 + rsub;          // rows rbase + 2t
    const int jbase = jh * 64;
#define PVROW(r, ac) { s[r].x += (ac) * hv.x; s[r].y += (ac) * hv.y; s[r].z += (ac) * hv.z; s[r].w += (ac) * hv.w; }
    for (int ck = 0; ck < 8; ++ck) {
        const int d0 = ck * 64;
        const float4* cur = (ck & 1) ? hB : hA;
        float4* nxt = (ck & 1) ? hA : hB;
        if (tid >= 512) {
            if (ck < 7) {
                #pragma unroll
                for (int q = 0; q < 4; ++q) {
                    int l = q * 512 + (tid - 512);
                    int row = l >> 4, c4 = l & 15;
                    nxt[row * 17 + (c4 ^ ((row >> 3) & 7))] = *(const float4*)(hb + row * DD + d0 + 64 + c4 * 4);
                }
            }
        } else {
            float4 s[8];
            #pragma unroll
            for (int r = 0; r < 8; ++r) s[r] = make_float4(0.f, 0.f, 0.f, 0.f);
            #pragma unroll 2
            for (int jq = 0; jq < 16; ++jq) {
                const int j0 = jbase + jq * 4;
                const int swz = (j0 >> 3) & 7;
                float4 av0 = *(const float4*)(&eselS[(rbase +  0) * 132 + j0]);
                float4 av1 = *(const float4*)(&eselS[(rbase +  2) * 132 + j0]);
                float4 av2 = *(const float4*)(&eselS[(rbase +  4) * 132 + j0]);
                float4 av3 = *(const float4*)(&eselS[(rbase +  6) * 132 + j0]);
                float4 av4 = *(const float4*)(&eselS[(rbase +  8) * 132 + j0]);
                float4 av5 = *(const float4*)(&eselS[(rbase + 10) * 132 + j0]);
                float4 av6 = *(const float4*)(&eselS[(rbase + 12) * 132 + j0]);
                float4 av7 = *(const float4*)(&eselS[(rbase + 14) * 132 + j0]);
                float4 hv;
                hv = cur[(j0 + 0) * 17 + (gd ^ swz)];
                PVROW(0, av0.x) PVROW(1, av1.x) PVROW(2, av2.x) PVROW(3, av3.x)
                PVROW(4, av4.x) PVROW(5, av5.x) PVROW(6, av6.x) PVROW(7, av7.x)
                hv = cur[(j0 + 1) * 17 + (gd ^ swz)];
                PVROW(0, av0.y) PVROW(1, av1.y) PVROW(2, av2.y) PVROW(3, av3.y)
                PVROW(4, av4.y) PVROW(5, av5.y) PVROW(6, av6.y) PVROW(7, av7.y)
                hv = cur[(j0 + 2) * 17 + (gd ^ swz)];
                PVROW(0, av0.z) PVROW(1, av1.z) PVROW(2, av2.z) PVROW(3, av3.z)
                PVROW(4, av4.z) PVROW(5, av5.z) PVROW(6, av6.z) PVROW(7, av7.z)
                hv = cur[(j0 + 3) * 17 + (gd ^ swz)];
                PVROW(0, av0.w) PVROW(1, av1.w) PVROW(2, av2.w) PVROW(3, av3.w)
                PVROW(4, av4.w) PVROW(5, av5.w) PVROW(6, av6.w) PVROW(7, av7.w)
            }
            #pragma unroll
            for (int r = 0; r < 8; ++r) {
                float mx = __shfl_xor(s[r].x, 16);
                float my = __shfl_xor(s[r].y, 16);
                float mz = __shfl_xor(s[r].z, 16);
                float mw = __shfl_xor(s[r].w, 16);
                s[r].x += mx; s[r].y += my; s[r].z += mz; s[r].w += mw;
            }
            if (jh == 0) {
                float* outp = h_gat + ((size_t)b * NN + rbase) * DD + d0 + gd * 4;
                #pragma unroll
                for (int r = 0; r < 8; ++r) *(float4*)(outp + (size_t)(2 * r) * DD) = s[r];
            }
        }
        __syncthreads();
    }
#undef PVROW
}

// ---------------------------------------------------------------- K2b: gate + noise + embs + sims (256-thread, spill-free)
// grid (8, B). Chains exactly R1 k_mix; sim = exact R1 k_attpool dot chain on hn.
// mode: 0 = no embs; 1 = deferred final (embs from h1,h2,hn); 2 = embs = hn/3; 3 = embs += hn/3.
__global__ __launch_bounds__(256) void k_mix(const float* __restrict__ h_gat,
                                             const float* __restrict__ star,
                                             const float* __restrict__ noise_s,
                                             const float* __restrict__ h1p,
                                             const float* __restrict__ h2p,
                                             float* __restrict__ h_out,
                                             float* __restrict__ embs,
                                             float* __restrict__ sims,
                                             int mode) {
    const int b = blockIdx.y;
    const int tid = threadIdx.x;
    const int wave = tid >> 6, lane = tid & 63;
    const int row0 = blockIdx.x * 16 + wave * 4;
    const float* stp = star + (size_t)b * DD + lane * 8;
    float4 st0 = *(const float4*)(stp);
    float4 st1 = *(const float4*)(stp + 4);
    const float inv3 = 1.0f / 3.0f;

    for (int rr = 0; rr < 4; ++rr) {
        const int row = row0 + rr;
        const size_t base = ((size_t)b * NN + row) * DD + lane * 8;
        float4 hg0 = *(const float4*)(h_gat + base);
        float4 hg1 = *(const float4*)(h_gat + base + 4);
        float4 n0 = *(const float4*)(noise_s + base);
        float4 n1 = *(const float4*)(noise_s + base + 4);
        float dot = hg0.x*st0.x + hg0.y*st0.y + hg0.z*st0.z + hg0.w*st0.w
                  + hg1.x*st1.x + hg1.y*st1.y + hg1.z*st1.z + hg1.w*st1.w;
        float nn = n0.x*n0.x + n0.y*n0.y + n0.z*n0.z + n0.w*n0.w
                 + n1.x*n1.x + n1.y*n1.y + n1.z*n1.z + n1.w*n1.w;
        #pragma unroll
        for (int off = 1; off < 64; off <<= 1) {
            dot += __shfl_xor(dot, off);
            nn  += __shfl_xor(nn, off);
        }
        const float sim = dot / 22.62741699796952f;   // / sqrt(512)
        const float al = 1.0f / (1.0f + expf(-sim));
        const float ns = 0.4f / fmaxf(sqrtf(nn), 1e-12f);

        float hm, sg, hn[8];
        float hgv[8] = {hg0.x,hg0.y,hg0.z,hg0.w,hg1.x,hg1.y,hg1.z,hg1.w};
        float stv[8] = {st0.x,st0.y,st0.z,st0.w,st1.x,st1.y,st1.z,st1.w};
        float nv [8] = {n0.x,n0.y,n0.z,n0.w,n1.x,n1.y,n1.z,n1.w};
        #pragma unroll
        for (int c = 0; c < 8; ++c) {
            hm = (1.0f - al) * hgv[c] + al * stv[c];
            sg = (hm > 0.f) ? 1.f : ((hm < 0.f) ? -1.f : 0.f);
            hn[c] = hm + sg * nv[c] * ns;
        }
        *(float4*)(h_out + base)     = make_float4(hn[0], hn[1], hn[2], hn[3]);
        *(float4*)(h_out + base + 4) = make_float4(hn[4], hn[5], hn[6], hn[7]);

        float d2 = hn[0]*stv[0] + hn[1]*stv[1] + hn[2]*stv[2] + hn[3]*stv[3]
                 + hn[4]*stv[4] + hn[5]*stv[5] + hn[6]*stv[6] + hn[7]*stv[7];
        #pragma unroll
        for (int off = 1; off < 64; off <<= 1) d2 += __shfl_xor(d2, off);
        if (lane == 0) sims[b * NN + row] = d2;

        if (mode == 1) {
            float4 a0v = *(const float4*)(h1p + base);
            float4 a1v = *(const float4*)(h1p + base + 4);
            float4 b0v = *(const float4*)(h2p + base);
            float4 b1v = *(const float4*)(h2p + base + 4);
            float h1v[8] = {a0v.x,a0v.y,a0v.z,a0v.w,a1v.x,a1v.y,a1v.z,a1v.w};
            float h2v[8] = {b0v.x,b0v.y,b0v.z,b0v.w,b1v.x,b1v.y,b1v.z,b1v.w};
            float ev[8];
            #pragma unroll
            for (int c = 0; c < 8; ++c) {
                float e = h1v[c] * inv3;
                e += h2v[c] * inv3;
                e += hn[c] * inv3;
                ev[c] = e;
            }
            *(float4*)(embs + base)     = make_float4(ev[0], ev[1], ev[2], ev[3]);
            *(float4*)(embs + base + 4) = make_float4(ev[4], ev[5], ev[6], ev[7]);
        } else if (mode == 2) {
            *(float4*)(embs + base)     = make_float4(hn[0]*inv3, hn[1]*inv3, hn[2]*inv3, hn[3]*inv3);
            *(float4*)(embs + base + 4) = make_float4(hn[4]*inv3, hn[5]*inv3, hn[6]*inv3, hn[7]*inv3);
        } else if (mode == 3) {
            float4 ea = *(const float4*)(embs + base);
            float4 eb = *(const float4*)(embs + base + 4);
            ea.x += hn[0]*inv3; ea.y += hn[1]*inv3; ea.z += hn[2]*inv3; ea.w += hn[3]*inv3;
            eb.x += hn[4]*inv3; eb.y += hn[5]*inv3; eb.z += hn[6]*inv3; eb.w += hn[7]*inv3;
            *(float4*)(embs + base)     = ea;
            *(float4*)(embs + base + 4) = eb;
        }
    }
}

// ---------------------------------------------------------------- K3: attpool from precomputed sims (one h pass)
__global__ __launch_bounds__(256) void k_attpool2(const float* __restrict__ h,
                                                  const float* __restrict__ sims,
                                                  const float* __restrict__ mask,
                                                  float* __restrict__ star_out) {
    __shared__ float simS[NN];
    __shared__ float wS[NN];
    __shared__ float sh_M, sh_inv;
    const int b = blockIdx.x;
    const int tid = threadIdx.x;
    if (tid < NN) simS[tid] = sims[b * NN + tid];
    __syncthreads();
    if (tid < 64) {
        float v = fmaxf(simS[tid], simS[tid + 64]);
        #pragma unroll
        for (int off = 1; off < 64; off <<= 1) v = fmaxf(v, __shfl_xor(v, off));
        if (tid == 0) sh_M = v;
    }
    __syncthreads();
    const float M = sh_M;
    if (tid < NN) wS[tid] = expf(simS[tid] - M) * mask[b * NN + tid];
    __syncthreads();
    if (tid < 64) {
        float v = wS[tid] + wS[tid + 64];
        #pragma unroll
        for (int off = 1; off < 64; off <<= 1) v += __shfl_xor(v, off);
        if (tid == 0) sh_inv = 1.0f / (v + 1e-24f * expf(-M));
    }
    __syncthreads();
    const float inv = sh_inv;
    const float* hb = h + (size_t)b * NN * DD;
    float acc0 = 0.f, acc1 = 0.f;
    for (int n = 0; n < NN; ++n) {
        const float w = wS[n];
        acc0 += w * hb[n * DD + tid];
        acc1 += w * hb[n * DD + tid + 256];
    }
    star_out[b * DD + tid] = acc0 * inv;
    star_out[b * DD + tid + 256] = acc1 * inv;
}

// ----------------------------------------------------------------
extern "C" void kernel_launch(void* const* d_in, const int* in_sizes, int n_in,
                              void* d_out, int out_size, void* d_ws, size_t ws_size,
                              hipStream_t stream) {
    const int*   A      = (const int*)d_in[0];
    const float* hidden = (const float*)d_in[1];
    const float* mask   = (const float*)d_in[2];
    const float* a0     = (const float*)d_in[3];
    const float* a1     = (const float*)d_in[4];
    const float* a2     = (const float*)d_in[5];
    const float* a3     = (const float*)d_in[6];
    const float* noise  = (const float*)d_in[7];

    float* out_h    = (float*)d_out;
    float* out_star = out_h + (size_t)BB * NN * DD;
    float* out_embs = out_star + (size_t)BB * DD;

    const size_t hElems = (size_t)BB * NN * DD;
    const size_t simsElems = (size_t)BB * NN;
    const size_t needDeferred = (2 * hElems + (size_t)BB * DD + simsElems) * sizeof(float);
    const bool deferred = ws_size >= needDeferred;

    float* ws_h1   = (float*)d_ws;
    float* ws_h2   = deferred ? (ws_h1 + hElems) : ws_h1;
    float* ws_star = (deferred ? ws_h2 : ws_h1) + hElems;
    float* ws_sims = ws_star + (size_t)BB * DD;

    k_avepool<<<BB, 256, 0, stream>>>(hidden, mask, ws_star);

    for (int s = 0; s < 3; ++s) {
        const float* hin = (s == 0) ? hidden : (deferred ? ((s == 1) ? ws_h1 : ws_h2) : ws_h1);
        k_gat<<<BB, 1024, 0, stream>>>(hin, A, a0, a1, a2, a3, out_h);

        const float* ns = noise + (size_t)s * BB * NN * DD;
        float* hout = (s == 2) ? out_h : (deferred ? ((s == 0) ? ws_h1 : ws_h2) : ws_h1);
        float* sout = (s == 2) ? out_star : ws_star;
        int mode;
        const float* h1p = nullptr; const float* h2p = nullptr;
        if (deferred) {
            if (s < 2) mode = 0;
            else { mode = 1; h1p = ws_h1; h2p = ws_h2; }
        } else {
            mode = (s == 0) ? 2 : 3;
        }
        k_mix<<<dim3(8, BB), 256, 0, stream>>>(out_h, ws_star, ns, h1p, h2p,
                                               hout, out_embs, ws_sims, mode);
        k_attpool2<<<BB, 256, 0, stream>>>(hout, ws_sims, mask, sout);
    }
}